// Round 5
// baseline (244.180 us; speedup 1.0000x reference)
//
#include <hip/hip_runtime.h>
#include <hip/hip_bf16.h>

#define BSZ 4
#define SEQ 2048
#define DIM 1024

typedef __attribute__((ext_vector_type(8))) short bf16x8;
typedef __attribute__((ext_vector_type(4))) float floatx4;

__device__ __forceinline__ unsigned short f2bf(float x) {
  union { float f; unsigned int u; } v; v.f = x;
  unsigned int r = v.u + 0x7fffu + ((v.u >> 16) & 1u);
  return (unsigned short)(r >> 16);
}

template <typename T> __device__ __forceinline__ void store_c(T* p, float v);
template <> __device__ __forceinline__ void store_c<float>(float* p, float v) { *p = v; }
template <> __device__ __forceinline__ void store_c<unsigned short>(unsigned short* p, float v) { *p = f2bf(v); }

// ---------------- cast fp32 -> bf16 (R6-proven) + Rsum zeroing (folded memset) ----------------
__global__ __launch_bounds__(256) void cast_e(const float* __restrict__ in,
                                              unsigned short* __restrict__ out, int n,
                                              float* __restrict__ rsum) {
  if (blockIdx.x < 8) {
    // zero BSZ*SEQ = 8192 floats of rowsum (8 blocks x 256 thr x 4 floats)
    int j = blockIdx.x * 1024 + threadIdx.x * 4;
    *(float4*)(rsum + j) = make_float4(0.f, 0.f, 0.f, 0.f);
  }
  int i = (blockIdx.x * 256 + threadIdx.x) * 4;
  if (i >= n) return;
  float4 v = *(const float4*)(in + i);
  ushort4 o;
  o.x = f2bf(v.x); o.y = f2bf(v.y); o.z = f2bf(v.z); o.w = f2bf(v.w);
  *(ushort4*)(out + i) = o;
}

// ---------------- transpose + cast weights (R6-proven) ----------------
__global__ __launch_bounds__(256) void transpose_w(const float* __restrict__ Wq,
                                                   const float* __restrict__ Wk,
                                                   const float* __restrict__ Wv,
                                                   unsigned short* __restrict__ WtQK,
                                                   unsigned short* __restrict__ WtV) {
  __shared__ float tile[32][33];
  int z = blockIdx.z;
  const float* W = (z == 0) ? Wq : (z == 1) ? Wk : Wv;
  unsigned short* dst = (z == 2) ? WtV : WtQK;
  int row_off = (z == 1) ? 1024 : 0;
  int n0 = blockIdx.x * 32, k0 = blockIdx.y * 32;
  int tx = threadIdx.x, ty = threadIdx.y;
  for (int r = ty; r < 32; r += 8)
    tile[r][tx] = W[(size_t)(k0 + r) * DIM + n0 + tx];
  __syncthreads();
  for (int r = ty; r < 32; r += 8)
    dst[(size_t)(row_off + n0 + r) * DIM + k0 + tx] = f2bf(tile[tx][r]);
}

__device__ __forceinline__ void gload16(const unsigned short* g, unsigned short* l) {
  __builtin_amdgcn_global_load_lds(
      (const __attribute__((address_space(1))) unsigned int*)g,
      (__attribute__((address_space(3))) unsigned int*)l, 16, 0, 0);
}

// =====================================================================
// 8-phase 256x256 GEMM core (QK path) — R4-verified, FROZEN.
// =====================================================================
__device__ __forceinline__ void proj8ph(
    const unsigned short* __restrict__ A,
    const unsigned short* __restrict__ Bm,
    unsigned short* __restrict__ C, int ldc, int m0, int n0,
    unsigned short* sA, unsigned short* sB) {
  const int tid = threadIdx.x;
  const int lane = tid & 63;
  const int wid = tid >> 6;            // 0..7
  const int wm = (wid >> 2) * 128;     // 0 / 128
  const int wn = (wid & 3) * 64;       // 0/64/128/192
  const int lr = lane & 15, lq = lane >> 4;

  unsigned short* aB = sA + (wm >> 7) * 8192 + lr * 64;
  unsigned short* bB = sB + (wn >> 7) * 8192 + ((wn & 64) + lr) * 64;
  const int sw0 = (lq ^ (lr & 7)) * 8;
  const int sw1 = ((4 + lq) ^ (lr & 7)) * 8;

  const int schunk = (tid & 7) ^ ((tid >> 3) & 7);
  const unsigned short* gA = A + (size_t)(m0 + (tid >> 3)) * DIM + schunk * 8;
  const unsigned short* gB = Bm + (size_t)(n0 + (tid >> 3)) * DIM + schunk * 8;
  unsigned short* lA = sA + wid * 512;
  unsigned short* lB = sB + wid * 512;

#define STG_A(buf, T, half) do { \
    gload16(gA + (size_t)((half) * 128) * DIM + (T) * 64,      lA + (buf) * 16384 + (half) * 8192); \
    gload16(gA + (size_t)((half) * 128 + 64) * DIM + (T) * 64, lA + (buf) * 16384 + (half) * 8192 + 4096); } while (0)
#define STG_B(buf, T, half) do { \
    gload16(gB + (size_t)((half) * 128) * DIM + (T) * 64,      lB + (buf) * 16384 + (half) * 8192); \
    gload16(gB + (size_t)((half) * 128 + 64) * DIM + (T) * 64, lB + (buf) * 16384 + (half) * 8192 + 4096); } while (0)
#define RD_A(buf, qr) do { _Pragma("unroll") for (int i_ = 0; i_ < 4; ++i_) { \
    af[i_][0] = *(const bf16x8*)(aB + (buf) * 16384 + ((qr) * 64 + i_ * 16) * 64 + sw0); \
    af[i_][1] = *(const bf16x8*)(aB + (buf) * 16384 + ((qr) * 64 + i_ * 16) * 64 + sw1); } } while (0)
#define RD_B(buf, qc) do { _Pragma("unroll") for (int j_ = 0; j_ < 2; ++j_) { \
    bq[qc][j_][0] = *(const bf16x8*)(bB + (buf) * 16384 + ((qc) * 32 + j_ * 16) * 64 + sw0); \
    bq[qc][j_][1] = *(const bf16x8*)(bB + (buf) * 16384 + ((qc) * 32 + j_ * 16) * 64 + sw1); } } while (0)
#define MM(qr, qc) do { __builtin_amdgcn_s_setprio(1); \
    _Pragma("unroll") for (int i_ = 0; i_ < 4; ++i_) \
    _Pragma("unroll") for (int jj_ = 0; jj_ < 2; ++jj_) { \
      acc[(qr)*4+i_][(qc)*2+jj_] = __builtin_amdgcn_mfma_f32_16x16x32_bf16(af[i_][0], bq[qc][jj_][0], acc[(qr)*4+i_][(qc)*2+jj_], 0, 0, 0); \
      acc[(qr)*4+i_][(qc)*2+jj_] = __builtin_amdgcn_mfma_f32_16x16x32_bf16(af[i_][1], bq[qc][jj_][1], acc[(qr)*4+i_][(qc)*2+jj_], 0, 0, 0); } \
    __builtin_amdgcn_s_setprio(0); } while (0)
#define BAR __builtin_amdgcn_s_barrier()
#define LGKM0 do { asm volatile("s_waitcnt lgkmcnt(0)" ::: "memory"); __builtin_amdgcn_sched_barrier(0); } while (0)
#define VM4 asm volatile("s_waitcnt vmcnt(4)" ::: "memory")
#define VM0 asm volatile("s_waitcnt vmcnt(0)" ::: "memory")

  floatx4 acc[8][4] = {};
  bf16x8 af[4][2], bq[2][2][2];

  STG_B(0, 0, 0); STG_B(0, 0, 1);
  STG_A(0, 0, 0); STG_A(0, 0, 1);
  STG_B(1, 1, 0); STG_B(1, 1, 1);
  VM4;
  BAR;

#pragma unroll 1
  for (int j = 0; j < 8; ++j) {
    const int t0 = 2 * j, t1 = 2 * j + 1;
    const bool st = (j < 7);
    RD_A(0, 0); RD_B(0, 0);
    STG_A(1, t1, 0);
    BAR; LGKM0; MM(0, 0); BAR;

    RD_B(0, 1);
    STG_A(1, t1, 1);
    BAR; LGKM0; MM(0, 1); BAR;

    RD_A(0, 1);
    if (st) STG_B(0, t0 + 2, 0);
    BAR; LGKM0; MM(1, 0); BAR;

    if (st) STG_B(0, t0 + 2, 1);
    BAR; MM(1, 1);
    if (st) { VM4; } else { VM0; }
    BAR;

    RD_A(1, 0); RD_B(1, 0);
    if (st) STG_A(0, t0 + 2, 0);
    BAR; LGKM0; MM(0, 0); BAR;

    RD_B(1, 1);
    if (st) STG_A(0, t0 + 2, 1);
    BAR; LGKM0; MM(0, 1); BAR;

    RD_A(1, 1);
    if (st) STG_B(1, t1 + 2, 0);
    BAR; LGKM0; MM(1, 0); BAR;

    if (st) STG_B(1, t1 + 2, 1);
    BAR; MM(1, 1);
    if (st) { VM4; }
    BAR;
  }
#undef STG_A
#undef STG_B
#undef RD_A
#undef RD_B
#undef MM
#undef BAR
#undef LGKM0
#undef VM4
#undef VM0

#pragma unroll
  for (int i = 0; i < 8; ++i) {
    int rbase = m0 + wm + i * 16 + lq * 4;
#pragma unroll
    for (int jc = 0; jc < 4; ++jc) {
      int col = n0 + wn + jc * 16 + lr;
#pragma unroll
      for (int r = 0; r < 4; ++r)
        C[(size_t)(rbase + r) * ldc + col] = f2bf(acc[i][jc][r]);
    }
  }
}

// ---------------- R2-proven ring-4 core (Vt half-work round) — FROZEN ----------------
#define NT_PROJ 32  // K=1024 / BK=32

template <int BMt>
__device__ __forceinline__ void proj_core(
    const unsigned short* __restrict__ A,
    const unsigned short* __restrict__ Bm,
    unsigned short* __restrict__ C, int ldc, int m0, int n0,
    unsigned short* sAr, unsigned short* sBr) {
  constexpr int LPA = BMt / 128;
  constexpr int LPT = LPA + 2;
  constexpr int FR  = BMt / 32;
  constexpr int TA  = BMt * 32;
  constexpr int TB  = 256 * 32;

  const int tid = threadIdx.x;
  const int lane = tid & 63;
  const int wid = tid >> 6;
  const int wm = (wid >> 2) * (BMt / 2);
  const int wn = (wid & 3) * 64;
  const int lr = lane & 15, lq = lane >> 4;

  const int srow = tid >> 2;
  const int schunk = (tid & 3) ^ ((tid >> 3) & 3);
  const unsigned short* gA = A + (size_t)(m0 + srow) * DIM + schunk * 8;
  const unsigned short* gB = Bm + (size_t)(n0 + srow) * DIM + schunk * 8;
  unsigned short* lA = sAr + 16 * 32 * wid;
  unsigned short* lB = sBr + 16 * 32 * wid;
  const size_t swG = (size_t)128 * DIM;

#define STAGE_A(T) do { int rb_ = (T) & 3; \
    gload16(gA + (size_t)(T) * 32, lA + rb_ * TA); \
    if constexpr (LPA == 2) gload16(gA + (size_t)(T) * 32 + swG, lA + rb_ * TA + 4096); } while (0)
#define STAGE_B(T) do { int rb_ = (T) & 3; \
    gload16(gB + (size_t)(T) * 32,       lB + rb_ * TB); \
    gload16(gB + (size_t)(T) * 32 + swG, lB + rb_ * TB + 4096); } while (0)
#define ARD(rb_, rowv) (*(const bf16x8*)&sAr[(rb_) * TA + (rowv) * 32 + (lq ^ (((rowv) >> 1) & 3)) * 8])
#define BRD(rb_, rowv) (*(const bf16x8*)&sBr[(rb_) * TB + (rowv) * 32 + (lq ^ (((rowv) >> 1) & 3)) * 8])

  floatx4 acc[FR][4] = {};

  STAGE_A(0); STAGE_B(0);
  STAGE_A(1); STAGE_B(1);
  STAGE_A(2); STAGE_B(2);
  if constexpr (LPT == 4) asm volatile("s_waitcnt vmcnt(8)" ::: "memory");
  else                    asm volatile("s_waitcnt vmcnt(6)" ::: "memory");
  __builtin_amdgcn_s_barrier();

#pragma unroll 4
  for (int T = 0; T < NT_PROJ; ++T) {
    const int rb = T & 3;
    bf16x8 af[4], bfr[4];
#pragma unroll
    for (int j = 0; j < 4; ++j) bfr[j] = BRD(rb, wn + j * 16 + lr);
#pragma unroll
    for (int i = 0; i < 4; ++i) af[i] = ARD(rb, wm + i * 16 + lr);
    if (T + 3 < NT_PROJ) {
      STAGE_A(T + 3);
      if constexpr (BMt == 128) STAGE_B(T + 3);
    }
    __builtin_amdgcn_s_barrier();
    __builtin_amdgcn_s_setprio(1);
#pragma unroll
    for (int i = 0; i < 4; ++i)
#pragma unroll
      for (int j = 0; j < 4; ++j)
        acc[i][j] = __builtin_amdgcn_mfma_f32_16x16x32_bf16(af[i], bfr[j], acc[i][j], 0, 0, 0);
    __builtin_amdgcn_s_setprio(0);
    if constexpr (BMt == 256) {
      __builtin_amdgcn_s_barrier();
#pragma unroll
      for (int i = 0; i < 4; ++i) af[i] = ARD(rb, wm + 64 + i * 16 + lr);
      if (T + 3 < NT_PROJ) STAGE_B(T + 3);
      __builtin_amdgcn_s_barrier();
      __builtin_amdgcn_s_setprio(1);
#pragma unroll
      for (int i = 0; i < 4; ++i)
#pragma unroll
        for (int j = 0; j < 4; ++j)
          acc[4 + i][j] = __builtin_amdgcn_mfma_f32_16x16x32_bf16(af[i], bfr[j], acc[4 + i][j], 0, 0, 0);
      __builtin_amdgcn_s_setprio(0);
    }
    if (T < NT_PROJ - 3) {
      if constexpr (LPT == 4) asm volatile("s_waitcnt vmcnt(8)" ::: "memory");
      else                    asm volatile("s_waitcnt vmcnt(6)" ::: "memory");
    } else if (T == NT_PROJ - 3) {
      if constexpr (LPT == 4) asm volatile("s_waitcnt vmcnt(4)" ::: "memory");
      else                    asm volatile("s_waitcnt vmcnt(3)" ::: "memory");
    } else if (T == NT_PROJ - 2) {
      asm volatile("s_waitcnt vmcnt(0)" ::: "memory");
    }
    __builtin_amdgcn_s_barrier();
  }
#undef STAGE_A
#undef STAGE_B
#undef ARD
#undef BRD

#pragma unroll
  for (int i = 0; i < FR; ++i) {
    int rbase = m0 + wm + i * 16 + lq * 4;
#pragma unroll
    for (int j = 0; j < 4; ++j) {
      int col = n0 + wn + j * 16 + lr;
#pragma unroll
      for (int r = 0; r < 4; ++r)
        C[(size_t)(rbase + r) * ldc + col] = f2bf(acc[i][j][r]);
    }
  }
}

__global__ __launch_bounds__(512, 2) void proj256(
    const unsigned short* __restrict__ Ebf,
    const unsigned short* __restrict__ WtQK,
    const unsigned short* __restrict__ WtV,
    unsigned short* __restrict__ QKo,
    unsigned short* __restrict__ Vt) {
  __shared__ __align__(16) unsigned short sA[32768];  // 64 KiB
  __shared__ __align__(16) unsigned short sB[32768];  // 64 KiB
  int x = blockIdx.x;
  if (x < 256) {
    proj8ph(Ebf, WtQK, QKo, 2 * DIM, (x >> 3) * 256, (x & 7) * 256, sA, sB);
  } else {
    x -= 256;
    proj_core<128>(WtV, Ebf, Vt, BSZ * SEQ, (x >> 5) * 128, (x & 31) * 256, sA, sB);
  }
}

// =====================================================================
// NEW: scores / PV on the R2-proven ring-4 core, 256-thread 128x128 variant.
// Same staging/swizzle/vmcnt-ladder schedule as proj_core (verified R2/R4),
// scaled to 4 waves: per K-tile(32) stage = 4 gload16 (A 2 sweeps of 64
// rows, B 2 sweeps), ring-4 (64 KiB LDS -> 2 blocks/CU), prefetch 3,
// counted vmcnt(8/4/0). Grid decode + epilogues verbatim from the old
// (passing) gemm_nt: MODE 1 = exp numerator + rowsum atomics (tri grid),
// MODE 2 = PV with causal Keff + divide by rowsum (longest-first).
// =====================================================================
template <typename OutT, int MODE>
__global__ __launch_bounds__(256, 2) void gemm_ring(
    const unsigned short* __restrict__ A, int lda, long long strideA,
    const unsigned short* __restrict__ B, int ldb, long long strideB,
    OutT* __restrict__ C, int ldc, long long strideC,
    int Kdim, float scale, float* __restrict__ rowsum) {
  int m0, n0;
  if constexpr (MODE == 1) {
    int t = blockIdx.x;           // packed lower-triangle decode
    int mt = 0;
    while (((mt + 1) * (mt + 2)) / 2 <= t) mt++;
    int nt = t - (mt * (mt + 1)) / 2;
    m0 = mt * 128; n0 = nt * 128;
  } else {
    m0 = (gridDim.y - 1 - blockIdx.y) * 128;  // longest blocks first
    n0 = blockIdx.x * 128;
  }
  const int Keff = (MODE == 2) ? min(Kdim, m0 + 128) : Kdim;
  const int NT = Keff >> 5;     // K-tiles of 32; NT >= 4 always here
  A += (long long)blockIdx.z * strideA;
  B += (long long)blockIdx.z * strideB;
  C += (long long)blockIdx.z * strideC;
  rowsum += (size_t)blockIdx.z * SEQ;

  __shared__ __align__(16) unsigned short sA[4 * 4096];  // 32 KiB
  __shared__ __align__(16) unsigned short sB[4 * 4096];  // 32 KiB

  const int tid = threadIdx.x;
  const int lane = tid & 63;
  const int wid = tid >> 6;                 // 0..3
  const int wm = (wid >> 1) * 64, wn = (wid & 1) * 64;
  const int lr = lane & 15, lq = lane >> 4;

  // staging: thread t -> row t>>2 (0..63; +64 for 2nd gload), swizzled chunk
  const int schunk = (tid & 3) ^ ((tid >> 3) & 3);
  const unsigned short* gA = A + (size_t)(m0 + (tid >> 2)) * lda + schunk * 8;
  const unsigned short* gB = B + (size_t)(n0 + (tid >> 2)) * ldb + schunk * 8;
  unsigned short* lA = sA + wid * 512;      // wave-uniform; HW adds lane*16B
  unsigned short* lB = sB + wid * 512;
  const size_t sGA = (size_t)64 * lda, sGB = (size_t)64 * ldb;

#define RSTAGE(T) do { int rb_ = (T) & 3; \
    gload16(gA + (size_t)(T) * 32,       lA + rb_ * 4096); \
    gload16(gA + (size_t)(T) * 32 + sGA, lA + rb_ * 4096 + 2048); \
    gload16(gB + (size_t)(T) * 32,       lB + rb_ * 4096); \
    gload16(gB + (size_t)(T) * 32 + sGB, lB + rb_ * 4096 + 2048); } while (0)
#define RARD(rb_, rowv) (*(const bf16x8*)&sA[(rb_) * 4096 + (rowv) * 32 + (lq ^ (((rowv) >> 1) & 3)) * 8])
#define RBRD(rb_, rowv) (*(const bf16x8*)&sB[(rb_) * 4096 + (rowv) * 32 + (lq ^ (((rowv) >> 1) & 3)) * 8])

  floatx4 acc[4][4] = {};

  RSTAGE(0); RSTAGE(1); RSTAGE(2);
  asm volatile("s_waitcnt vmcnt(8)" ::: "memory");  // land tile 0 (oldest 4 of 12)
  __builtin_amdgcn_s_barrier();

  for (int T = 0; T < NT; ++T) {
    const int rb = T & 3;
    bf16x8 af[4], bfr[4];
#pragma unroll
    for (int j = 0; j < 4; ++j) bfr[j] = RBRD(rb, wn + j * 16 + lr);
#pragma unroll
    for (int i = 0; i < 4; ++i) af[i] = RARD(rb, wm + i * 16 + lr);
    if (T + 3 < NT) RSTAGE(T + 3);
    __builtin_amdgcn_s_barrier();
    __builtin_amdgcn_s_setprio(1);
#pragma unroll
    for (int i = 0; i < 4; ++i)
#pragma unroll
      for (int j = 0; j < 4; ++j)
        acc[i][j] = __builtin_amdgcn_mfma_f32_16x16x32_bf16(af[i], bfr[j], acc[i][j], 0, 0, 0);
    __builtin_amdgcn_s_setprio(0);
    // counted ladder (R2-proven): steady vm(8) lands tile T+1; tail 4 -> 0
    if (T < NT - 3)       asm volatile("s_waitcnt vmcnt(8)" ::: "memory");
    else if (T == NT - 3) asm volatile("s_waitcnt vmcnt(4)" ::: "memory");
    else if (T == NT - 2) asm volatile("s_waitcnt vmcnt(0)" ::: "memory");
    __builtin_amdgcn_s_barrier();
  }
#undef RSTAGE
#undef RARD
#undef RBRD

  // epilogues verbatim from the passing gemm_nt
  if constexpr (MODE == 1) {
#pragma unroll
    for (int i = 0; i < 4; i++) {
      int rbase = m0 + wm + i * 16 + lq * 4;
      float s0 = 0.f, s1 = 0.f, s2 = 0.f, s3 = 0.f;
#pragma unroll
      for (int j = 0; j < 4; j++) {
        int col = n0 + wn + j * 16 + lr;
        float e0 = (col <= rbase + 0) ? __expf(acc[i][j][0] * scale) : 0.0f;
        float e1 = (col <= rbase + 1) ? __expf(acc[i][j][1] * scale) : 0.0f;
        float e2 = (col <= rbase + 2) ? __expf(acc[i][j][2] * scale) : 0.0f;
        float e3 = (col <= rbase + 3) ? __expf(acc[i][j][3] * scale) : 0.0f;
        store_c(&C[(size_t)(rbase + 0) * ldc + col], e0);
        store_c(&C[(size_t)(rbase + 1) * ldc + col], e1);
        store_c(&C[(size_t)(rbase + 2) * ldc + col], e2);
        store_c(&C[(size_t)(rbase + 3) * ldc + col], e3);
        s0 += e0; s1 += e1; s2 += e2; s3 += e3;
      }
#pragma unroll
      for (int m = 1; m < 16; m <<= 1) {
        s0 += __shfl_xor(s0, m, 64);
        s1 += __shfl_xor(s1, m, 64);
        s2 += __shfl_xor(s2, m, 64);
        s3 += __shfl_xor(s3, m, 64);
      }
      if (lr == 0) {
        atomicAdd(&rowsum[rbase + 0], s0);
        atomicAdd(&rowsum[rbase + 1], s1);
        atomicAdd(&rowsum[rbase + 2], s2);
        atomicAdd(&rowsum[rbase + 3], s3);
      }
    }
  } else {
#pragma unroll
    for (int i = 0; i < 4; i++) {
      int rbase = m0 + wm + i * 16 + lq * 4;
      float i0 = 1.0f / rowsum[rbase + 0];
      float i1 = 1.0f / rowsum[rbase + 1];
      float i2 = 1.0f / rowsum[rbase + 2];
      float i3 = 1.0f / rowsum[rbase + 3];
#pragma unroll
      for (int j = 0; j < 4; j++) {
        int col = n0 + wn + j * 16 + lr;
        store_c(&C[(size_t)(rbase + 0) * ldc + col], acc[i][j][0] * i0);
        store_c(&C[(size_t)(rbase + 1) * ldc + col], acc[i][j][1] * i1);
        store_c(&C[(size_t)(rbase + 2) * ldc + col], acc[i][j][2] * i2);
        store_c(&C[(size_t)(rbase + 3) * ldc + col], acc[i][j][3] * i3);
      }
    }
  }
}

extern "C" void kernel_launch(void* const* d_in, const int* in_sizes, int n_in,
                              void* d_out, int out_size, void* d_ws, size_t ws_size,
                              hipStream_t stream) {
  const float* E  = (const float*)d_in[0];
  const float* Wq = (const float*)d_in[1];
  const float* Wk = (const float*)d_in[2];
  const float* Wv = (const float*)d_in[3];
  float* out = (float*)d_out;

  char* ws = (char*)d_ws;
  size_t off = 0;
  auto alloc = [&](size_t bytes) {
    void* p = ws + off;
    off += (bytes + 255) & ~(size_t)255;
    return p;
  };
  const size_t M_ALL = (size_t)BSZ * SEQ;
  unsigned short* Ebf  = (unsigned short*)alloc(M_ALL * DIM * 2);
  unsigned short* WtQK = (unsigned short*)alloc((size_t)2 * DIM * DIM * 2);
  unsigned short* WtV  = (unsigned short*)alloc((size_t)DIM * DIM * 2);
  unsigned short* QK   = (unsigned short*)alloc(M_ALL * 2 * DIM * 2);
  unsigned short* Vt   = (unsigned short*)alloc((size_t)DIM * M_ALL * 2);
  unsigned short* ExpS = (unsigned short*)alloc((size_t)BSZ * SEQ * SEQ * 2);
  float*          Rsum = (float*)alloc((size_t)BSZ * SEQ * 4);

  int nE = (int)(M_ALL * DIM);
  cast_e<<<dim3(nE / (256 * 4)), dim3(256), 0, stream>>>(E, Ebf, nE, Rsum);
  transpose_w<<<dim3(32, 32, 3), dim3(32, 8), 0, stream>>>(Wq, Wk, Wv, WtQK, WtV);

  // fused QK (256 blocks, 8-phase core) + Vt (256 half-work blocks, ring core)
  proj256<<<dim3(512), dim3(512), 0, stream>>>(Ebf, WtQK, WtV, QK, Vt);

  // scores -> exp numerators (bf16) + rowsum atomics; packed triangular grid
  gemm_ring<unsigned short, 1><<<dim3(136, 1, BSZ), dim3(256), 0, stream>>>(
      QK, 2 * DIM, (long long)SEQ * 2 * DIM,
      QK + DIM, 2 * DIM, (long long)SEQ * 2 * DIM,
      ExpS, SEQ, (long long)SEQ * SEQ,
      DIM, 0.03125f /* 1/sqrt(1024) */, Rsum);

  // PV: out[q][d] = (sum_k expS[q][k] * Vt[d][k]) / rowsum[q]
  gemm_ring<float, 2><<<dim3(8, 16, BSZ), dim3(256), 0, stream>>>(
      ExpS, SEQ, (long long)SEQ * SEQ,
      Vt, (int)M_ALL, (long long)SEQ,
      out, DIM, (long long)SEQ * DIM,
      SEQ, 1.0f, Rsum);
}

// Round 6
// 234.826 us; speedup vs baseline: 1.0398x; 1.0398x over previous
//
#include <hip/hip_runtime.h>
#include <hip/hip_bf16.h>

#define BSZ 4
#define SEQ 2048
#define DIM 1024

typedef __attribute__((ext_vector_type(8))) short bf16x8;
typedef __attribute__((ext_vector_type(4))) float floatx4;

__device__ __forceinline__ unsigned short f2bf(float x) {
  union { float f; unsigned int u; } v; v.f = x;
  unsigned int r = v.u + 0x7fffu + ((v.u >> 16) & 1u);
  return (unsigned short)(r >> 16);
}

template <typename T> __device__ __forceinline__ void store_c(T* p, float v);
template <> __device__ __forceinline__ void store_c<float>(float* p, float v) { *p = v; }
template <> __device__ __forceinline__ void store_c<unsigned short>(unsigned short* p, float v) { *p = f2bf(v); }

// ---------------- merged prep: cast E -> bf16, zero rowsum, transpose+cast weights ----------------
// blocks [0, 8192): cast_e body (R6-proven); first 8 also zero Rsum.
// blocks [8192, 11264): transpose_w body (R6-proven), z = (b-8192)/1024.
__global__ __launch_bounds__(256) void prep(const float* __restrict__ E,
                                            const float* __restrict__ Wq,
                                            const float* __restrict__ Wk,
                                            const float* __restrict__ Wv,
                                            unsigned short* __restrict__ Ebf,
                                            unsigned short* __restrict__ WtQK,
                                            unsigned short* __restrict__ WtV,
                                            float* __restrict__ rsum, int n) {
  __shared__ float tile[32][33];
  int b = blockIdx.x;
  int tid = threadIdx.x;
  if (b < 8192) {
    if (b < 8) {
      int j = b * 1024 + tid * 4;
      *(float4*)(rsum + j) = make_float4(0.f, 0.f, 0.f, 0.f);
    }
    int i = (b * 256 + tid) * 4;
    if (i >= n) return;
    float4 v = *(const float4*)(E + i);
    ushort4 o;
    o.x = f2bf(v.x); o.y = f2bf(v.y); o.z = f2bf(v.z); o.w = f2bf(v.w);
    *(ushort4*)(Ebf + i) = o;
  } else {
    b -= 8192;
    int z = b >> 10;             // 0..2
    int rb = b & 1023;
    int bx = rb & 31, by = rb >> 5;
    const float* W = (z == 0) ? Wq : (z == 1) ? Wk : Wv;
    unsigned short* dst = (z == 2) ? WtV : WtQK;
    int row_off = (z == 1) ? 1024 : 0;
    int n0 = bx * 32, k0 = by * 32;
    int tx = tid & 31, ty = tid >> 5;   // 32 x 8
    for (int r = ty; r < 32; r += 8)
      tile[r][tx] = W[(size_t)(k0 + r) * DIM + n0 + tx];
    __syncthreads();
    for (int r = ty; r < 32; r += 8)
      dst[(size_t)(row_off + n0 + r) * DIM + k0 + tx] = f2bf(tile[tx][r]);
  }
}

__device__ __forceinline__ void gload16(const unsigned short* g, unsigned short* l) {
  __builtin_amdgcn_global_load_lds(
      (const __attribute__((address_space(1))) unsigned int*)g,
      (__attribute__((address_space(3))) unsigned int*)l, 16, 0, 0);
}

// =====================================================================
// 8-phase 256x256 GEMM core (QK path) — R4-verified, FROZEN.
// =====================================================================
__device__ __forceinline__ void proj8ph(
    const unsigned short* __restrict__ A,
    const unsigned short* __restrict__ Bm,
    unsigned short* __restrict__ C, int ldc, int m0, int n0,
    unsigned short* sA, unsigned short* sB) {
  const int tid = threadIdx.x;
  const int lane = tid & 63;
  const int wid = tid >> 6;            // 0..7
  const int wm = (wid >> 2) * 128;     // 0 / 128
  const int wn = (wid & 3) * 64;       // 0/64/128/192
  const int lr = lane & 15, lq = lane >> 4;

  unsigned short* aB = sA + (wm >> 7) * 8192 + lr * 64;
  unsigned short* bB = sB + (wn >> 7) * 8192 + ((wn & 64) + lr) * 64;
  const int sw0 = (lq ^ (lr & 7)) * 8;
  const int sw1 = ((4 + lq) ^ (lr & 7)) * 8;

  const int schunk = (tid & 7) ^ ((tid >> 3) & 7);
  const unsigned short* gA = A + (size_t)(m0 + (tid >> 3)) * DIM + schunk * 8;
  const unsigned short* gB = Bm + (size_t)(n0 + (tid >> 3)) * DIM + schunk * 8;
  unsigned short* lA = sA + wid * 512;
  unsigned short* lB = sB + wid * 512;

#define STG_A(buf, T, half) do { \
    gload16(gA + (size_t)((half) * 128) * DIM + (T) * 64,      lA + (buf) * 16384 + (half) * 8192); \
    gload16(gA + (size_t)((half) * 128 + 64) * DIM + (T) * 64, lA + (buf) * 16384 + (half) * 8192 + 4096); } while (0)
#define STG_B(buf, T, half) do { \
    gload16(gB + (size_t)((half) * 128) * DIM + (T) * 64,      lB + (buf) * 16384 + (half) * 8192); \
    gload16(gB + (size_t)((half) * 128 + 64) * DIM + (T) * 64, lB + (buf) * 16384 + (half) * 8192 + 4096); } while (0)
#define RD_A(buf, qr) do { _Pragma("unroll") for (int i_ = 0; i_ < 4; ++i_) { \
    af[i_][0] = *(const bf16x8*)(aB + (buf) * 16384 + ((qr) * 64 + i_ * 16) * 64 + sw0); \
    af[i_][1] = *(const bf16x8*)(aB + (buf) * 16384 + ((qr) * 64 + i_ * 16) * 64 + sw1); } } while (0)
#define RD_B(buf, qc) do { _Pragma("unroll") for (int j_ = 0; j_ < 2; ++j_) { \
    bq[qc][j_][0] = *(const bf16x8*)(bB + (buf) * 16384 + ((qc) * 32 + j_ * 16) * 64 + sw0); \
    bq[qc][j_][1] = *(const bf16x8*)(bB + (buf) * 16384 + ((qc) * 32 + j_ * 16) * 64 + sw1); } } while (0)
#define MM(qr, qc) do { __builtin_amdgcn_s_setprio(1); \
    _Pragma("unroll") for (int i_ = 0; i_ < 4; ++i_) \
    _Pragma("unroll") for (int jj_ = 0; jj_ < 2; ++jj_) { \
      acc[(qr)*4+i_][(qc)*2+jj_] = __builtin_amdgcn_mfma_f32_16x16x32_bf16(af[i_][0], bq[qc][jj_][0], acc[(qr)*4+i_][(qc)*2+jj_], 0, 0, 0); \
      acc[(qr)*4+i_][(qc)*2+jj_] = __builtin_amdgcn_mfma_f32_16x16x32_bf16(af[i_][1], bq[qc][jj_][1], acc[(qr)*4+i_][(qc)*2+jj_], 0, 0, 0); } \
    __builtin_amdgcn_s_setprio(0); } while (0)
#define BAR __builtin_amdgcn_s_barrier()
#define LGKM0 do { asm volatile("s_waitcnt lgkmcnt(0)" ::: "memory"); __builtin_amdgcn_sched_barrier(0); } while (0)
#define VM4 asm volatile("s_waitcnt vmcnt(4)" ::: "memory")
#define VM0 asm volatile("s_waitcnt vmcnt(0)" ::: "memory")

  floatx4 acc[8][4] = {};
  bf16x8 af[4][2], bq[2][2][2];

  STG_B(0, 0, 0); STG_B(0, 0, 1);
  STG_A(0, 0, 0); STG_A(0, 0, 1);
  STG_B(1, 1, 0); STG_B(1, 1, 1);
  VM4;
  BAR;

#pragma unroll 1
  for (int j = 0; j < 8; ++j) {
    const int t0 = 2 * j, t1 = 2 * j + 1;
    const bool st = (j < 7);
    RD_A(0, 0); RD_B(0, 0);
    STG_A(1, t1, 0);
    BAR; LGKM0; MM(0, 0); BAR;

    RD_B(0, 1);
    STG_A(1, t1, 1);
    BAR; LGKM0; MM(0, 1); BAR;

    RD_A(0, 1);
    if (st) STG_B(0, t0 + 2, 0);
    BAR; LGKM0; MM(1, 0); BAR;

    if (st) STG_B(0, t0 + 2, 1);
    BAR; MM(1, 1);
    if (st) { VM4; } else { VM0; }
    BAR;

    RD_A(1, 0); RD_B(1, 0);
    if (st) STG_A(0, t0 + 2, 0);
    BAR; LGKM0; MM(0, 0); BAR;

    RD_B(1, 1);
    if (st) STG_A(0, t0 + 2, 1);
    BAR; LGKM0; MM(0, 1); BAR;

    RD_A(1, 1);
    if (st) STG_B(1, t1 + 2, 0);
    BAR; LGKM0; MM(1, 0); BAR;

    if (st) STG_B(1, t1 + 2, 1);
    BAR; MM(1, 1);
    if (st) { VM4; }
    BAR;
  }
#undef STG_A
#undef STG_B
#undef RD_A
#undef RD_B
#undef MM
#undef BAR
#undef LGKM0
#undef VM4
#undef VM0

#pragma unroll
  for (int i = 0; i < 8; ++i) {
    int rbase = m0 + wm + i * 16 + lq * 4;
#pragma unroll
    for (int jc = 0; jc < 4; ++jc) {
      int col = n0 + wn + jc * 16 + lr;
#pragma unroll
      for (int r = 0; r < 4; ++r)
        C[(size_t)(rbase + r) * ldc + col] = f2bf(acc[i][jc][r]);
    }
  }
}

// ---------------- R2-proven ring-4 core (Vt half-work round) — FROZEN ----------------
#define NT_PROJ 32  // K=1024 / BK=32

template <int BMt>
__device__ __forceinline__ void proj_core(
    const unsigned short* __restrict__ A,
    const unsigned short* __restrict__ Bm,
    unsigned short* __restrict__ C, int ldc, int m0, int n0,
    unsigned short* sAr, unsigned short* sBr) {
  constexpr int LPA = BMt / 128;
  constexpr int LPT = LPA + 2;
  constexpr int FR  = BMt / 32;
  constexpr int TA  = BMt * 32;
  constexpr int TB  = 256 * 32;

  const int tid = threadIdx.x;
  const int lane = tid & 63;
  const int wid = tid >> 6;
  const int wm = (wid >> 2) * (BMt / 2);
  const int wn = (wid & 3) * 64;
  const int lr = lane & 15, lq = lane >> 4;

  const int srow = tid >> 2;
  const int schunk = (tid & 3) ^ ((tid >> 3) & 3);
  const unsigned short* gA = A + (size_t)(m0 + srow) * DIM + schunk * 8;
  const unsigned short* gB = Bm + (size_t)(n0 + srow) * DIM + schunk * 8;
  unsigned short* lA = sAr + 16 * 32 * wid;
  unsigned short* lB = sBr + 16 * 32 * wid;
  const size_t swG = (size_t)128 * DIM;

#define STAGE_A(T) do { int rb_ = (T) & 3; \
    gload16(gA + (size_t)(T) * 32, lA + rb_ * TA); \
    if constexpr (LPA == 2) gload16(gA + (size_t)(T) * 32 + swG, lA + rb_ * TA + 4096); } while (0)
#define STAGE_B(T) do { int rb_ = (T) & 3; \
    gload16(gB + (size_t)(T) * 32,       lB + rb_ * TB); \
    gload16(gB + (size_t)(T) * 32 + swG, lB + rb_ * TB + 4096); } while (0)
#define ARD(rb_, rowv) (*(const bf16x8*)&sAr[(rb_) * TA + (rowv) * 32 + (lq ^ (((rowv) >> 1) & 3)) * 8])
#define BRD(rb_, rowv) (*(const bf16x8*)&sBr[(rb_) * TB + (rowv) * 32 + (lq ^ (((rowv) >> 1) & 3)) * 8])

  floatx4 acc[FR][4] = {};

  STAGE_A(0); STAGE_B(0);
  STAGE_A(1); STAGE_B(1);
  STAGE_A(2); STAGE_B(2);
  if constexpr (LPT == 4) asm volatile("s_waitcnt vmcnt(8)" ::: "memory");
  else                    asm volatile("s_waitcnt vmcnt(6)" ::: "memory");
  __builtin_amdgcn_s_barrier();

#pragma unroll 4
  for (int T = 0; T < NT_PROJ; ++T) {
    const int rb = T & 3;
    bf16x8 af[4], bfr[4];
#pragma unroll
    for (int j = 0; j < 4; ++j) bfr[j] = BRD(rb, wn + j * 16 + lr);
#pragma unroll
    for (int i = 0; i < 4; ++i) af[i] = ARD(rb, wm + i * 16 + lr);
    if (T + 3 < NT_PROJ) {
      STAGE_A(T + 3);
      if constexpr (BMt == 128) STAGE_B(T + 3);
    }
    __builtin_amdgcn_s_barrier();
    __builtin_amdgcn_s_setprio(1);
#pragma unroll
    for (int i = 0; i < 4; ++i)
#pragma unroll
      for (int j = 0; j < 4; ++j)
        acc[i][j] = __builtin_amdgcn_mfma_f32_16x16x32_bf16(af[i], bfr[j], acc[i][j], 0, 0, 0);
    __builtin_amdgcn_s_setprio(0);
    if constexpr (BMt == 256) {
      __builtin_amdgcn_s_barrier();
#pragma unroll
      for (int i = 0; i < 4; ++i) af[i] = ARD(rb, wm + 64 + i * 16 + lr);
      if (T + 3 < NT_PROJ) STAGE_B(T + 3);
      __builtin_amdgcn_s_barrier();
      __builtin_amdgcn_s_setprio(1);
#pragma unroll
      for (int i = 0; i < 4; ++i)
#pragma unroll
        for (int j = 0; j < 4; ++j)
          acc[4 + i][j] = __builtin_amdgcn_mfma_f32_16x16x32_bf16(af[i], bfr[j], acc[4 + i][j], 0, 0, 0);
      __builtin_amdgcn_s_setprio(0);
    }
    if (T < NT_PROJ - 3) {
      if constexpr (LPT == 4) asm volatile("s_waitcnt vmcnt(8)" ::: "memory");
      else                    asm volatile("s_waitcnt vmcnt(6)" ::: "memory");
    } else if (T == NT_PROJ - 3) {
      if constexpr (LPT == 4) asm volatile("s_waitcnt vmcnt(4)" ::: "memory");
      else                    asm volatile("s_waitcnt vmcnt(3)" ::: "memory");
    } else if (T == NT_PROJ - 2) {
      asm volatile("s_waitcnt vmcnt(0)" ::: "memory");
    }
    __builtin_amdgcn_s_barrier();
  }
#undef STAGE_A
#undef STAGE_B
#undef ARD
#undef BRD

#pragma unroll
  for (int i = 0; i < FR; ++i) {
    int rbase = m0 + wm + i * 16 + lq * 4;
#pragma unroll
    for (int j = 0; j < 4; ++j) {
      int col = n0 + wn + j * 16 + lr;
#pragma unroll
      for (int r = 0; r < 4; ++r)
        C[(size_t)(rbase + r) * ldc + col] = f2bf(acc[i][j][r]);
    }
  }
}

__global__ __launch_bounds__(512, 2) void proj256(
    const unsigned short* __restrict__ Ebf,
    const unsigned short* __restrict__ WtQK,
    const unsigned short* __restrict__ WtV,
    unsigned short* __restrict__ QKo,
    unsigned short* __restrict__ Vt) {
  __shared__ __align__(16) unsigned short sA[32768];  // 64 KiB
  __shared__ __align__(16) unsigned short sB[32768];  // 64 KiB
  int x = blockIdx.x;
  if (x < 256) {
    proj8ph(Ebf, WtQK, QKo, 2 * DIM, (x >> 3) * 256, (x & 7) * 256, sA, sB);
  } else {
    x -= 256;
    proj_core<128>(WtV, Ebf, Vt, BSZ * SEQ, (x >> 5) * 128, (x & 31) * 256, sA, sB);
  }
}

// =====================================================================
// scores / PV on the R2-proven ring-4 core (R5-verified), 256-thread 128x128.
// R6 change: MODE 2 decode gains complementary pairing — co-resident block
// pairs (x,y,z) and (x,y,z+2) now decode COMPLEMENTARY causal Keff
// (flip y for z>=2), so per-CU work sums are constant (2176 K-rows)
// instead of worst-case 2x imbalance.
// =====================================================================
template <typename OutT, int MODE>
__global__ __launch_bounds__(256, 2) void gemm_ring(
    const unsigned short* __restrict__ A, int lda, long long strideA,
    const unsigned short* __restrict__ B, int ldb, long long strideB,
    OutT* __restrict__ C, int ldc, long long strideC,
    int Kdim, float scale, float* __restrict__ rowsum) {
  int m0, n0;
  if constexpr (MODE == 1) {
    int t = blockIdx.x;           // packed lower-triangle decode
    int mt = 0;
    while (((mt + 1) * (mt + 2)) / 2 <= t) mt++;
    int nt = t - (mt * (mt + 1)) / 2;
    m0 = mt * 128; n0 = nt * 128;
  } else {
    // complementary pairing: z<2 longest-first, z>=2 shortest-first
    int yy = ((blockIdx.z >> 1) & 1) ? blockIdx.y : (gridDim.y - 1 - blockIdx.y);
    m0 = yy * 128;
    n0 = blockIdx.x * 128;
  }
  const int Keff = (MODE == 2) ? min(Kdim, m0 + 128) : Kdim;
  const int NT = Keff >> 5;     // K-tiles of 32; NT >= 4 always here
  A += (long long)blockIdx.z * strideA;
  B += (long long)blockIdx.z * strideB;
  C += (long long)blockIdx.z * strideC;
  rowsum += (size_t)blockIdx.z * SEQ;

  __shared__ __align__(16) unsigned short sA[4 * 4096];  // 32 KiB
  __shared__ __align__(16) unsigned short sB[4 * 4096];  // 32 KiB

  const int tid = threadIdx.x;
  const int lane = tid & 63;
  const int wid = tid >> 6;                 // 0..3
  const int wm = (wid >> 1) * 64, wn = (wid & 1) * 64;
  const int lr = lane & 15, lq = lane >> 4;

  const int schunk = (tid & 3) ^ ((tid >> 3) & 3);
  const unsigned short* gA = A + (size_t)(m0 + (tid >> 2)) * lda + schunk * 8;
  const unsigned short* gB = B + (size_t)(n0 + (tid >> 2)) * ldb + schunk * 8;
  unsigned short* lA = sA + wid * 512;      // wave-uniform; HW adds lane*16B
  unsigned short* lB = sB + wid * 512;
  const size_t sGA = (size_t)64 * lda, sGB = (size_t)64 * ldb;

#define RSTAGE(T) do { int rb_ = (T) & 3; \
    gload16(gA + (size_t)(T) * 32,       lA + rb_ * 4096); \
    gload16(gA + (size_t)(T) * 32 + sGA, lA + rb_ * 4096 + 2048); \
    gload16(gB + (size_t)(T) * 32,       lB + rb_ * 4096); \
    gload16(gB + (size_t)(T) * 32 + sGB, lB + rb_ * 4096 + 2048); } while (0)
#define RARD(rb_, rowv) (*(const bf16x8*)&sA[(rb_) * 4096 + (rowv) * 32 + (lq ^ (((rowv) >> 1) & 3)) * 8])
#define RBRD(rb_, rowv) (*(const bf16x8*)&sB[(rb_) * 4096 + (rowv) * 32 + (lq ^ (((rowv) >> 1) & 3)) * 8])

  floatx4 acc[4][4] = {};

  RSTAGE(0); RSTAGE(1); RSTAGE(2);
  asm volatile("s_waitcnt vmcnt(8)" ::: "memory");  // land tile 0 (oldest 4 of 12)
  __builtin_amdgcn_s_barrier();

  for (int T = 0; T < NT; ++T) {
    const int rb = T & 3;
    bf16x8 af[4], bfr[4];
#pragma unroll
    for (int j = 0; j < 4; ++j) bfr[j] = RBRD(rb, wn + j * 16 + lr);
#pragma unroll
    for (int i = 0; i < 4; ++i) af[i] = RARD(rb, wm + i * 16 + lr);
    if (T + 3 < NT) RSTAGE(T + 3);
    __builtin_amdgcn_s_barrier();
    __builtin_amdgcn_s_setprio(1);
#pragma unroll
    for (int i = 0; i < 4; ++i)
#pragma unroll
      for (int j = 0; j < 4; ++j)
        acc[i][j] = __builtin_amdgcn_mfma_f32_16x16x32_bf16(af[i], bfr[j], acc[i][j], 0, 0, 0);
    __builtin_amdgcn_s_setprio(0);
    if (T < NT - 3)       asm volatile("s_waitcnt vmcnt(8)" ::: "memory");
    else if (T == NT - 3) asm volatile("s_waitcnt vmcnt(4)" ::: "memory");
    else if (T == NT - 2) asm volatile("s_waitcnt vmcnt(0)" ::: "memory");
    __builtin_amdgcn_s_barrier();
  }
#undef RSTAGE
#undef RARD
#undef RBRD

  if constexpr (MODE == 1) {
#pragma unroll
    for (int i = 0; i < 4; i++) {
      int rbase = m0 + wm + i * 16 + lq * 4;
      float s0 = 0.f, s1 = 0.f, s2 = 0.f, s3 = 0.f;
#pragma unroll
      for (int j = 0; j < 4; j++) {
        int col = n0 + wn + j * 16 + lr;
        float e0 = (col <= rbase + 0) ? __expf(acc[i][j][0] * scale) : 0.0f;
        float e1 = (col <= rbase + 1) ? __expf(acc[i][j][1] * scale) : 0.0f;
        float e2 = (col <= rbase + 2) ? __expf(acc[i][j][2] * scale) : 0.0f;
        float e3 = (col <= rbase + 3) ? __expf(acc[i][j][3] * scale) : 0.0f;
        store_c(&C[(size_t)(rbase + 0) * ldc + col], e0);
        store_c(&C[(size_t)(rbase + 1) * ldc + col], e1);
        store_c(&C[(size_t)(rbase + 2) * ldc + col], e2);
        store_c(&C[(size_t)(rbase + 3) * ldc + col], e3);
        s0 += e0; s1 += e1; s2 += e2; s3 += e3;
      }
#pragma unroll
      for (int m = 1; m < 16; m <<= 1) {
        s0 += __shfl_xor(s0, m, 64);
        s1 += __shfl_xor(s1, m, 64);
        s2 += __shfl_xor(s2, m, 64);
        s3 += __shfl_xor(s3, m, 64);
      }
      if (lr == 0) {
        atomicAdd(&rowsum[rbase + 0], s0);
        atomicAdd(&rowsum[rbase + 1], s1);
        atomicAdd(&rowsum[rbase + 2], s2);
        atomicAdd(&rowsum[rbase + 3], s3);
      }
    }
  } else {
#pragma unroll
    for (int i = 0; i < 4; i++) {
      int rbase = m0 + wm + i * 16 + lq * 4;
      float i0 = 1.0f / rowsum[rbase + 0];
      float i1 = 1.0f / rowsum[rbase + 1];
      float i2 = 1.0f / rowsum[rbase + 2];
      float i3 = 1.0f / rowsum[rbase + 3];
#pragma unroll
      for (int j = 0; j < 4; j++) {
        int col = n0 + wn + j * 16 + lr;
        store_c(&C[(size_t)(rbase + 0) * ldc + col], acc[i][j][0] * i0);
        store_c(&C[(size_t)(rbase + 1) * ldc + col], acc[i][j][1] * i1);
        store_c(&C[(size_t)(rbase + 2) * ldc + col], acc[i][j][2] * i2);
        store_c(&C[(size_t)(rbase + 3) * ldc + col], acc[i][j][3] * i3);
      }
    }
  }
}

extern "C" void kernel_launch(void* const* d_in, const int* in_sizes, int n_in,
                              void* d_out, int out_size, void* d_ws, size_t ws_size,
                              hipStream_t stream) {
  const float* E  = (const float*)d_in[0];
  const float* Wq = (const float*)d_in[1];
  const float* Wk = (const float*)d_in[2];
  const float* Wv = (const float*)d_in[3];
  float* out = (float*)d_out;

  char* ws = (char*)d_ws;
  size_t off = 0;
  auto alloc = [&](size_t bytes) {
    void* p = ws + off;
    off += (bytes + 255) & ~(size_t)255;
    return p;
  };
  const size_t M_ALL = (size_t)BSZ * SEQ;
  unsigned short* Ebf  = (unsigned short*)alloc(M_ALL * DIM * 2);
  unsigned short* WtQK = (unsigned short*)alloc((size_t)2 * DIM * DIM * 2);
  unsigned short* WtV  = (unsigned short*)alloc((size_t)DIM * DIM * 2);
  unsigned short* QK   = (unsigned short*)alloc(M_ALL * 2 * DIM * 2);
  unsigned short* Vt   = (unsigned short*)alloc((size_t)DIM * M_ALL * 2);
  unsigned short* ExpS = (unsigned short*)alloc((size_t)BSZ * SEQ * SEQ * 2);
  float*          Rsum = (float*)alloc((size_t)BSZ * SEQ * 4);

  int nE = (int)(M_ALL * DIM);
  // merged: cast E + zero Rsum + transpose weights (one dispatch)
  prep<<<dim3(8192 + 3072), dim3(256), 0, stream>>>(E, Wq, Wk, Wv, Ebf, WtQK, WtV, Rsum, nE);

  // fused QK (256 blocks, 8-phase core) + Vt (256 half-work blocks, ring core)
  proj256<<<dim3(512), dim3(512), 0, stream>>>(Ebf, WtQK, WtV, QK, Vt);

  // scores -> exp numerators (bf16) + rowsum atomics; packed triangular grid
  gemm_ring<unsigned short, 1><<<dim3(136, 1, BSZ), dim3(256), 0, stream>>>(
      QK, 2 * DIM, (long long)SEQ * 2 * DIM,
      QK + DIM, 2 * DIM, (long long)SEQ * 2 * DIM,
      ExpS, SEQ, (long long)SEQ * SEQ,
      DIM, 0.03125f /* 1/sqrt(1024) */, Rsum);

  // PV: out[q][d] = (sum_k expS[q][k] * Vt[d][k]) / rowsum[q]
  gemm_ring<float, 2><<<dim3(8, 16, BSZ), dim3(256), 0, stream>>>(
      ExpS, SEQ, (long long)SEQ * SEQ,
      Vt, (int)M_ALL, (long long)SEQ,
      out, DIM, (long long)SEQ * DIM,
      SEQ, 1.0f, Rsum);
}